// Round 18
// baseline (776.031 us; speedup 1.0000x reference)
//
#include <hip/hip_runtime.h>
#include <hip/hip_bf16.h>

#define N_EDGES 500000
#define N_NODES 50000
#define NT ((N_EDGES + 63) / 64)  // 7813 tiles of 64 edges
#define GRID 256
#define LN_EPS 1e-5f

typedef __attribute__((ext_vector_type(8))) short bf16x8;
typedef __attribute__((ext_vector_type(4))) short bf16x4;
typedef __attribute__((ext_vector_type(4))) float f32x4;

static __device__ __forceinline__ short f2bf(float f) {
  return __builtin_bit_cast(short, __float2bfloat16(f));
}
static __device__ __forceinline__ float bf2f(short s) {
  unsigned u = ((unsigned)(unsigned short)s) << 16;
  return __builtin_bit_cast(float, u);
}
static __device__ __forceinline__ void gload16(const void* g, void* l) {
  __builtin_amdgcn_global_load_lds(
      (const __attribute__((address_space(1))) unsigned int*)g,
      (__attribute__((address_space(3))) unsigned int*)l, 16, 0, 0);
}
static __device__ __forceinline__ void pin(bf16x8& v) {
  asm volatile("" : "+v"(v));
}
// lgkm-only barrier: does NOT drain in-flight global_load_lds
static __device__ __forceinline__ void bar_lds() {
  __builtin_amdgcn_sched_barrier(0);
  asm volatile("s_waitcnt lgkmcnt(0)" ::: "memory");
  __builtin_amdgcn_s_barrier();
  __builtin_amdgcn_sched_barrier(0);
}
static __device__ __forceinline__ void fence_lds() {
  asm volatile("s_waitcnt lgkmcnt(0)" ::: "memory");
  __builtin_amdgcn_sched_barrier(0);
}

// w1t [128n][384k] bf16, w2t [128n][128k] bf16, nbf = bf16(nfeat), + passthrough
__global__ void convert_kernel(const float* __restrict__ W1,
                               const float* __restrict__ W2,
                               const float* __restrict__ nfeat,
                               short* __restrict__ w1t, short* __restrict__ w2t,
                               short* __restrict__ nbf, float* __restrict__ outn) {
  const int step = gridDim.x * blockDim.x;
  const int t0 = blockIdx.x * blockDim.x + threadIdx.x;
  for (int i = t0; i < 384 * 128; i += step) {
    int n = i / 384, k = i - n * 384;
    w1t[i] = f2bf(W1[k * 128 + n]);
  }
  for (int i = t0; i < 128 * 128; i += step) {
    int n = i >> 7, k = i & 127;
    w2t[i] = f2bf(W2[k * 128 + n]);
  }
  for (int i = t0; i < N_NODES * 128 / 4; i += step) {
    f32x4 v = *(const f32x4*)(nfeat + (size_t)i * 4);
    short o4[4];
#pragma unroll
    for (int q = 0; q < 4; ++q) o4[q] = f2bf(v[q]);
    *(unsigned long long*)(nbf + (size_t)i * 4) = *(unsigned long long*)o4;
    *(f32x4*)(outn + (size_t)i * 4) = v;  // passthrough output 1
  }
}

// Wave-specialized persistent pipeline: 256 blocks (1/CU) x 512 thr.
// Waves 0-3 (A): GEMM1(tile i) + SiLU -> H[i&1].  W1 col-strip pinned (96 reg).
// Waves 4-7 (B): GEMM2+LN+flush(tile i-1) + ALL staging/gathers/stores.
//   B-wave owns 16 edges x all 128 cols -> LN wave-local. Full W2 pinned (128).
// One lgkm-only barrier per iteration = pipeline tick. Counted vmcnt(8).
__global__ __launch_bounds__(512, 2) void edge_mlp_ws(
    const float* __restrict__ efeat, const short* __restrict__ nbf,
    const int* __restrict__ src, const int* __restrict__ dst,
    const short* __restrict__ w1t, const short* __restrict__ w2t,
    const float* __restrict__ b1, const float* __restrict__ b2,
    const float* __restrict__ gamma, const float* __restrict__ beta,
    float* __restrict__ out) {
  __shared__ __align__(16) char smem[131072];
  // layout: EF(p)=smem+p*16384 [64][256B]; GBUF(p)=smem+32768+p*32768
  // [64][512B]; HB(p)=smem+98304+p*16384 [64][256B]  (all bf16, swizzled)

  const int tid = threadIdx.x;
  const int lane = tid & 63;
  const int w = tid >> 6;
  const int lrow = lane & 15;
  const int kgrp = (lane >> 4) & 3;
  const bool isA = (w < 4);
  const int t0 = blockIdx.x;
  const int nblk = (NT - 1 - t0) / GRID + 1;  // tiles for this block

  // ---------------- per-group persistent state ----------------
  bf16x8 B1r[12][2];  // A: W1 strip
  float b1v[2];
  bf16x8 B2r[4][8];   // B: full W2
  float b2v[8], gv[8], bev[8];
  const int bw = (w >= 4) ? (w - 4) : 0;  // B-wave 0..3
  const int frow = bw * 16 + (lane >> 2); // B flush/stage row
  const int fc = (lane & 3) * 32;         // B flush/stage col start
  const int fswz = (frow & 15) << 4;
  int grow[8], goff[8], gseg[8], idxN[8];

  if (isA) {
    const int aw = w;
#pragma unroll
    for (int n = 0; n < 2; ++n) {
      int c = aw * 32 + n * 16 + lrow;
      b1v[n] = b1[c];
#pragma unroll
      for (int ks = 0; ks < 12; ++ks) {
        B1r[ks][n] = *(const bf16x8*)(w1t + c * 384 + ks * 32 + kgrp * 8);
        pin(B1r[ks][n]);
      }
    }
  } else {
#pragma unroll
    for (int n = 0; n < 8; ++n) {
      int c = n * 16 + lrow;
      b2v[n] = b2[c];
      gv[n] = gamma[c];
      bev[n] = beta[c];
#pragma unroll
      for (int ks = 0; ks < 4; ++ks) {
        B2r[ks][n] = *(const bf16x8*)(w2t + c * 128 + ks * 32 + kgrp * 8);
        pin(B2r[ks][n]);
      }
    }
#pragma unroll
    for (int i = 0; i < 8; ++i) {
      int F = bw * 8192 + i * 1024 + lane * 16;  // linear byte in gather buf
      grow[i] = F >> 9;
      int win = F & 511;
      gseg[i] = win >> 8;
      goff[i] = (win & 255) ^ ((grow[i] & 15) << 4);  // pre-swizzle involution
    }
  }

  f32x4 S[8];
  auto stage_S = [&](int t) {
    int e = t * 64 + frow;
    e = e < N_EDGES ? e : (N_EDGES - 1);
    const float* p = efeat + (size_t)e * 128 + fc;
#pragma unroll
    for (int q = 0; q < 8; ++q) S[q] = *(const f32x4*)(p + q * 4);
  };
  auto write_ef = [&](char* buf) {
#pragma unroll
    for (int c = 0; c < 4; ++c) {
      bf16x8 v;
#pragma unroll
      for (int j = 0; j < 4; ++j) {
        v[j] = f2bf(S[2 * c][j]);
        v[4 + j] = f2bf(S[2 * c + 1][j]);
      }
      *(bf16x8*)(buf + frow * 256 + ((fc * 2 + c * 16) ^ fswz)) = v;
    }
  };
  auto load_idx = [&](int t, int* ix) {
#pragma unroll
    for (int i = 0; i < 8; ++i) {
      int e = t * 64 + grow[i];
      e = (e < N_EDGES && e >= 0) ? e : (N_EDGES - 1);
      ix[i] = gseg[i] ? dst[e] : src[e];
    }
  };
  auto issue_g = [&](char* buf, const int* ix) {
#pragma unroll
    for (int i = 0; i < 8; ++i)
      gload16((const char*)nbf + (size_t)ix[i] * 256 + goff[i],
              buf + bw * 8192 + i * 1024);
  };

  // ---------------- prologue (B stages tile T0) ----------------
  if (!isA) {
    int ix0[8];
    load_idx(t0, ix0);
    stage_S(t0);
    write_ef(smem);  // EF(0)
    __builtin_amdgcn_sched_barrier(0);
    issue_g(smem + 32768, ix0);  // GBUF(0)
    __builtin_amdgcn_sched_barrier(0);
    load_idx(t0 + GRID, idxN);
    asm volatile("s_waitcnt vmcnt(0)" ::: "memory");
  }
  __syncthreads();

  // ---------------- pipeline: A on tile i, B on tile i-1 ----------------
  for (int i = 0; i < nblk + 1; ++i) {
    const int p = i & 1;
    char* EFp = smem + p * 16384;
    char* EFq = smem + (p ^ 1) * 16384;
    char* GBp = smem + 32768 + p * 32768;
    char* GBq = smem + 32768 + (p ^ 1) * 32768;
    char* HBp = smem + 98304 + p * 16384;
    char* HBq = smem + 98304 + (p ^ 1) * 16384;
    const int tCur = t0 + i * GRID;
    if (isA) {
      if (i < nblk) {
        const int aw = w;
        f32x4 acc[4][2];
#pragma unroll
        for (int m = 0; m < 4; ++m)
#pragma unroll
          for (int n = 0; n < 2; ++n) acc[m][n] = (f32x4)0.f;
#pragma unroll
        for (int ks = 0; ks < 12; ++ks) {
          bf16x8 a[4];
#pragma unroll
          for (int m = 0; m < 4; ++m) {
            int row = m * 16 + lrow;
            int sw = (row & 15) << 4;
            a[m] = (ks < 4)
                       ? *(const bf16x8*)(EFp + row * 256 +
                                          ((ks * 64 + kgrp * 16) ^ sw))
                       : *(const bf16x8*)(GBp + row * 512 +
                                          (((ks - 4) * 64 + kgrp * 16) ^ sw));
          }
#pragma unroll
          for (int m = 0; m < 4; ++m)
#pragma unroll
            for (int n = 0; n < 2; ++n)
              acc[m][n] = __builtin_amdgcn_mfma_f32_16x16x32_bf16(
                  a[m], B1r[ks][n], acc[m][n], 0, 0, 0);
        }
        // bias1 + SiLU -> H[p]
#pragma unroll
        for (int m = 0; m < 4; ++m)
#pragma unroll
          for (int n = 0; n < 2; ++n)
#pragma unroll
            for (int r = 0; r < 4; ++r) {
              float x = acc[m][n][r] + b1v[n];
              float h = x / (1.f + __expf(-x));
              int row = m * 16 + kgrp * 4 + r;
              int col = aw * 32 + n * 16 + lrow;
              *(short*)(HBp + row * 256 + ((col * 2) ^ ((row & 15) << 4))) =
                  f2bf(h);
            }
      }
    } else {
      const int tPrev = tCur - GRID;
      const int tNext = tCur + GRID;
      const bool doFlush = (i >= 1);
      const bool doStage = (i + 1 < nblk);

      // residual capture for T(i-1) before EF[p^1] is overwritten (same thread)
      bf16x8 rz[4];
      if (doFlush) {
#pragma unroll
        for (int c = 0; c < 4; ++c)
          rz[c] = *(const bf16x8*)(EFq + frow * 256 +
                                   ((fc * 2 + c * 16) ^ fswz));
      }
      if (doStage) {
        stage_S(tNext);
        write_ef(EFq);  // ef(T(i+1))
      }
      __builtin_amdgcn_sched_barrier(0);
      if (doStage) issue_g(GBq, idxN);  // gathers(T(i+1))
      __builtin_amdgcn_sched_barrier(0);
      load_idx(tCur + 2 * GRID, idxN);  // unconditional (8 younger VMEM)

      if (doFlush) {
        // ---- GEMM2: tile T(i-1), own 16 edges x 128 cols ----
        f32x4 acc2[8];
#pragma unroll
        for (int n = 0; n < 8; ++n) acc2[n] = (f32x4)0.f;
        const int row2 = bw * 16 + lrow;
        const int sw2 = (row2 & 15) << 4;
#pragma unroll
        for (int ks = 0; ks < 4; ++ks) {
          bf16x8 a2 = *(const bf16x8*)(HBq + row2 * 256 +
                                       ((ks * 64 + kgrp * 16) ^ sw2));
#pragma unroll
          for (int n = 0; n < 8; ++n)
            acc2[n] = __builtin_amdgcn_mfma_f32_16x16x32_bf16(
                a2, B2r[ks][n], acc2[n], 0, 0, 0);
        }
        fence_lds();  // H reads done before bounce overwrites same rows

        // ---- LN (wave-local: lane's 8 cols, 16-lane reduce) ----
        float mu[4], rs[4];
#pragma unroll
        for (int r = 0; r < 4; ++r) {
          float s1 = 0.f, s2 = 0.f;
#pragma unroll
          for (int n = 0; n < 8; ++n) {
            float x = acc2[n][r] + b2v[n];
            s1 += x;
            s2 += x * x;
          }
          s1 += __shfl_xor(s1, 1, 64); s2 += __shfl_xor(s2, 1, 64);
          s1 += __shfl_xor(s1, 2, 64); s2 += __shfl_xor(s2, 2, 64);
          s1 += __shfl_xor(s1, 4, 64); s2 += __shfl_xor(s2, 4, 64);
          s1 += __shfl_xor(s1, 8, 64); s2 += __shfl_xor(s2, 8, 64);
          mu[r] = s1 * (1.f / 128.f);
          float var = s2 * (1.f / 128.f) - mu[r] * mu[r];
          rs[r] = rsqrtf(var + LN_EPS);
        }
        // ---- y = LN(x)*gamma+beta -> bounce into own H rows (bf16) ----
#pragma unroll
        for (int n = 0; n < 8; ++n)
#pragma unroll
          for (int r = 0; r < 4; ++r) {
            float x = acc2[n][r] + b2v[n];
            float y = (x - mu[r]) * rs[r] * gv[n] + bev[n];
            int row = bw * 16 + kgrp * 4 + r;
            int c2 = (n * 16 + lrow) * 2;
            *(short*)(HBq + row * 256 + (c2 ^ ((row & 15) << 4))) = f2bf(y);
          }
        fence_lds();  // bounce visible (same wave)

        // ---- flush own rows: y + residual -> out (coalesced) ----
        int e = tPrev * 64 + frow;
        if (e < N_EDGES) {
          float* op = out + (size_t)e * 128 + fc;
#pragma unroll
          for (int c = 0; c < 4; ++c) {
            bf16x8 yv = *(const bf16x8*)(HBq + frow * 256 +
                                         ((fc * 2 + c * 16) ^ fswz));
            f32x4 o0, o1;
#pragma unroll
            for (int j = 0; j < 4; ++j) {
              o0[j] = bf2f(yv[j]) + bf2f(rz[c][j]);
              o1[j] = bf2f(yv[4 + j]) + bf2f(rz[c][4 + j]);
            }
            *(f32x4*)(op + c * 8) = o0;
            *(f32x4*)(op + c * 8 + 4) = o1;
          }
        }
      }
      // drain this iteration's gathers (idx loads are younger; stores allowed out)
      asm volatile("s_waitcnt vmcnt(8)" ::: "memory");
    }
    bar_lds();  // pipeline tick (lgkm-only; stores may stay in flight)
  }
  asm volatile("s_waitcnt vmcnt(0)" ::: "memory");
}

// ---- fallback (tiny ws): block-per-edge, fp32 ----
__global__ void edge_simple(const float* __restrict__ efeat, const float* __restrict__ nfeat,
                            const int* __restrict__ src, const int* __restrict__ dst,
                            const float* __restrict__ W1, const float* __restrict__ b1,
                            const float* __restrict__ W2, const float* __restrict__ b2,
                            const float* __restrict__ g, const float* __restrict__ be,
                            float* __restrict__ out) {
  int e = blockIdx.x, j = threadIdx.x;
  __shared__ float cat[384], h[128], red[128];
  cat[j] = efeat[(size_t)e * 128 + j];
  cat[128 + j] = nfeat[(size_t)src[e] * 128 + j];
  cat[256 + j] = nfeat[(size_t)dst[e] * 128 + j];
  __syncthreads();
  float s = b1[j];
  for (int k = 0; k < 384; ++k) s += cat[k] * W1[k * 128 + j];
  h[j] = s / (1.f + expf(-s));
  __syncthreads();
  float o = b2[j];
  for (int k = 0; k < 128; ++k) o += h[k] * W2[k * 128 + j];
  red[j] = o;
  __syncthreads();
  __shared__ float mu, rs;
  if (j == 0) {
    float s1 = 0, s2 = 0;
    for (int k = 0; k < 128; ++k) { s1 += red[k]; s2 += red[k] * red[k]; }
    mu = s1 / 128.f;
    rs = rsqrtf(s2 / 128.f - mu * mu + LN_EPS);
  }
  __syncthreads();
  out[(size_t)e * 128 + j] = (o - mu) * rs * g[j] + be[j] + efeat[(size_t)e * 128 + j];
}

extern "C" void kernel_launch(void* const* d_in, const int* in_sizes, int n_in,
                              void* d_out, int out_size, void* d_ws, size_t ws_size,
                              hipStream_t stream) {
  const float* efeat = (const float*)d_in[0];
  const float* nfeat = (const float*)d_in[1];
  const int* src = (const int*)d_in[2];
  const int* dst = (const int*)d_in[3];
  const float* W1 = (const float*)d_in[4];
  const float* b1 = (const float*)d_in[5];
  const float* W2 = (const float*)d_in[6];
  const float* b2 = (const float*)d_in[7];
  const float* gamma = (const float*)d_in[8];
  const float* beta = (const float*)d_in[9];
  float* out = (float*)d_out;

  short* w1t = (short*)d_ws;         // 96 KB
  short* w2t = w1t + 384 * 128;      // 32 KB
  short* nbf = w2t + 128 * 128;      // 12.8 MB
  const size_t need =
      (size_t)(384 * 128 + 128 * 128 + (size_t)N_NODES * 128) * sizeof(short);

  if (ws_size >= need) {
    convert_kernel<<<1024, 256, 0, stream>>>(W1, W2, nfeat, w1t, w2t, nbf,
                                             out + (size_t)N_EDGES * 128);
    edge_mlp_ws<<<GRID, 512, 0, stream>>>(efeat, nbf, src, dst, w1t, w2t,
                                          b1, b2, gamma, beta, out);
  } else {
    hipMemcpyAsync(out + (size_t)N_EDGES * 128, nfeat,
                   (size_t)N_NODES * 128 * sizeof(float),
                   hipMemcpyDeviceToDevice, stream);
    edge_simple<<<N_EDGES, 128, 0, stream>>>(efeat, nfeat, src, dst, W1, b1, W2,
                                             b2, gamma, beta, out);
  }
}

// Round 20
// 420.094 us; speedup vs baseline: 1.8473x; 1.8473x over previous
//
#include <hip/hip_runtime.h>
#include <hip/hip_bf16.h>

#define N_EDGES 500000
#define N_NODES 50000
#define NT2 ((N_EDGES + 127) / 128)  // 3907 tiles of 128 edges
#define GRID 256
#define LN_EPS 1e-5f

typedef __attribute__((ext_vector_type(8))) short bf16x8;
typedef __attribute__((ext_vector_type(4))) short bf16x4;
typedef __attribute__((ext_vector_type(4))) float f32x4;

static __device__ __forceinline__ short f2bf(float f) {
  return __builtin_bit_cast(short, __float2bfloat16(f));
}
static __device__ __forceinline__ float bf2f(short s) {
  unsigned u = ((unsigned)(unsigned short)s) << 16;
  return __builtin_bit_cast(float, u);
}
static __device__ __forceinline__ void gload16(const void* g, void* l) {
  __builtin_amdgcn_global_load_lds(
      (const __attribute__((address_space(1))) unsigned int*)g,
      (__attribute__((address_space(3))) unsigned int*)l, 16, 0, 0);
}
static __device__ __forceinline__ void pin(bf16x8& v) {
  asm volatile("" : "+v"(v));
}
// lgkm-only barrier: does NOT drain in-flight global_load_lds
static __device__ __forceinline__ void bar_lds() {
  __builtin_amdgcn_sched_barrier(0);
  asm volatile("s_waitcnt lgkmcnt(0)" ::: "memory");
  __builtin_amdgcn_s_barrier();
  __builtin_amdgcn_sched_barrier(0);
}

// w1t [128n][384k] bf16, w2t [128n][128k] bf16, nbf = bf16(nfeat), + passthrough
__global__ void convert_kernel(const float* __restrict__ W1,
                               const float* __restrict__ W2,
                               const float* __restrict__ nfeat,
                               short* __restrict__ w1t, short* __restrict__ w2t,
                               short* __restrict__ nbf, float* __restrict__ outn) {
  const int step = gridDim.x * blockDim.x;
  const int t0 = blockIdx.x * blockDim.x + threadIdx.x;
  for (int i = t0; i < 384 * 128; i += step) {
    int n = i / 384, k = i - n * 384;
    w1t[i] = f2bf(W1[k * 128 + n]);
  }
  for (int i = t0; i < 128 * 128; i += step) {
    int n = i >> 7, k = i & 127;
    w2t[i] = f2bf(W2[k * 128 + n]);
  }
  for (int i = t0; i < N_NODES * 128 / 4; i += step) {
    f32x4 v = *(const f32x4*)(nfeat + (size_t)i * 4);
    short o4[4];
#pragma unroll
    for (int q = 0; q < 4; ++q) o4[q] = f2bf(v[q]);
    *(unsigned long long*)(nbf + (size_t)i * 4) = *(unsigned long long*)o4;
    *(f32x4*)(outn + (size_t)i * 4) = v;  // passthrough output 1
  }
}

// Persistent pipelined, TILE=128, full 160KiB LDS, 1 block/CU, 8 waves.
// Wave (wm,wn)=(w>>2,w&3): rows [wm*64,+64) x cols [wn*32,+32). Weights pinned.
// LDS: efb 32K @0 (single) | G0 64K @32768 | G1 64K @98304.
// H overlays Gcur[0:32K), xb overlays Gcur[32K:64K) after barB.
// Barriers/tile: A(=syncthreads, loads aged a full tile) + B/C/D (lgkm-only).
__global__ __launch_bounds__(512, 2) void edge_mlp_t128(
    const float* __restrict__ efeat, const short* __restrict__ nbf,
    const int* __restrict__ src, const int* __restrict__ dst,
    const short* __restrict__ w1t, const short* __restrict__ w2t,
    const float* __restrict__ b1, const float* __restrict__ b2,
    const float* __restrict__ gamma, const float* __restrict__ beta,
    float* __restrict__ out) {
  __shared__ __align__(16) char smem[163840];
  char* efb = smem;  // [128][256B] bf16 swz

  const int tid = threadIdx.x;
  const int lane = tid & 63;
  const int w = tid >> 6;      // 0..7
  const int wm = w >> 2;       // row-half 0/1 (rows wm*64..+64)
  const int wn = w & 3;        // col-quarter 0..3
  const int lrow = lane & 15;
  const int kgrp = (lane >> 4) & 3;

  // ---- weights loaded ONCE, pinned ----
  bf16x8 B1r[12][2], B2r[4][2];
  float b1v[2], b2v[2];
#pragma unroll
  for (int n = 0; n < 2; ++n) {
    const int c = wn * 32 + n * 16 + lrow;
    b1v[n] = b1[c];
    b2v[n] = b2[c];
#pragma unroll
    for (int ks = 0; ks < 12; ++ks) {
      B1r[ks][n] = *(const bf16x8*)(w1t + c * 384 + ks * 32 + kgrp * 8);
      pin(B1r[ks][n]);
    }
#pragma unroll
    for (int ks = 0; ks < 4; ++ks) {
      B2r[ks][n] = *(const bf16x8*)(w2t + c * 128 + ks * 32 + kgrp * 8);
      pin(B2r[ks][n]);
    }
  }

  // gather statics: 8 gload16/wave/tile; pre-swizzled source (involution)
  int grow[8], goff[8], gseg[8];
#pragma unroll
  for (int i = 0; i < 8; ++i) {
    int F = w * 8192 + i * 1024 + lane * 16;  // linear byte in 64K gather buf
    grow[i] = F >> 9;                         // row 0..127
    int win = F & 511;
    gseg[i] = win >> 8;
    goff[i] = (win & 255) ^ ((grow[i] & 15) << 4);
  }
  // stage/flush mapping: 4 threads/row, 32 cols each
  const int frow = tid >> 2;      // 0..127
  const int fc = (tid & 3) * 32;  // col start
  const int fswz = (frow & 15) << 4;

  f32x4 S[8];
  auto stage_S = [&](int t) {
    int e = t * 128 + frow;
    e = e < N_EDGES ? e : (N_EDGES - 1);
    const float* p = efeat + (size_t)e * 128 + fc;
#pragma unroll
    for (int q = 0; q < 8; ++q) S[q] = *(const f32x4*)(p + q * 4);
  };
  auto write_ef = [&]() {
#pragma unroll
    for (int c = 0; c < 4; ++c) {
      bf16x8 v;
#pragma unroll
      for (int j = 0; j < 4; ++j) {
        v[j] = f2bf(S[2 * c][j]);
        v[4 + j] = f2bf(S[2 * c + 1][j]);
      }
      *(bf16x8*)(efb + frow * 256 + ((fc * 2 + c * 16) ^ fswz)) = v;
    }
  };
  int idxN[8];
  auto load_idx = [&](int t, int* ix) {
#pragma unroll
    for (int i = 0; i < 8; ++i) {
      int e = t * 128 + grow[i];
      e = (e < N_EDGES && e >= 0) ? e : (N_EDGES - 1);
      ix[i] = gseg[i] ? dst[e] : src[e];
    }
  };
  auto issue_g = [&](char* buf, const int* ix) {
#pragma unroll
    for (int i = 0; i < 8; ++i)
      gload16((const char*)nbf + (size_t)ix[i] * 256 + goff[i],
              buf + w * 8192 + i * 1024);
  };

  // ---- prologue ----
  const int t0 = blockIdx.x;
  {
    stage_S(t0);
    write_ef();  // ef(t0)
    int ix0[8];
    load_idx(t0, ix0);
    issue_g(smem + 32768, ix0);  // gathers(t0) -> G0
    load_idx(t0 + GRID, idxN);
  }

  for (int t = t0, it = 0; t < NT2; t += GRID, ++it) {
    const int p = it & 1;
    char* cur = smem + 32768 + p * 65536;
    char* nxt = smem + 32768 + (p ^ 1) * 65536;
    char* Hb = cur;           // overlays gather rows' seg1 after barB
    char* xb = cur + 32768;   // overlays seg2 after barB

    __syncthreads();  // A: gathers(t)+ef(t) aged ~a full tile; all visible

    stage_S(t + GRID);   // ef(t+1) -> regs (issued before gathers: older)
    issue_g(nxt, idxN);  // gathers(t+1) -> nxt (free since flush(t-1) done)
    load_idx(t + 2 * GRID, idxN);

    // ---- GEMM1: K=384 (efb k<128, cur k>=128), B pinned ----
    f32x4 acc[4][2];
#pragma unroll
    for (int m = 0; m < 4; ++m)
#pragma unroll
      for (int n = 0; n < 2; ++n) acc[m][n] = (f32x4)0.f;
#pragma unroll
    for (int ks = 0; ks < 12; ++ks) {
      bf16x8 a[4];
#pragma unroll
      for (int m = 0; m < 4; ++m) {
        int row = wm * 64 + m * 16 + lrow;
        int sw = (row & 15) << 4;
        a[m] = (ks < 4)
                   ? *(const bf16x8*)(efb + row * 256 + ((ks * 64 + kgrp * 16) ^ sw))
                   : *(const bf16x8*)(cur + row * 512 +
                                      (((ks - 4) * 64 + kgrp * 16) ^ sw));
      }
#pragma unroll
      for (int m = 0; m < 4; ++m)
#pragma unroll
        for (int n = 0; n < 2; ++n)
          acc[m][n] = __builtin_amdgcn_mfma_f32_16x16x32_bf16(a[m], B1r[ks][n],
                                                              acc[m][n], 0, 0, 0);
    }
    bar_lds();  // B: all GEMM1 reads of cur complete -> H/xb may overlay

    // ---- bias1 + SiLU -> H (overlays cur[0:32K)) ----
#pragma unroll
    for (int m = 0; m < 4; ++m)
#pragma unroll
      for (int n = 0; n < 2; ++n)
#pragma unroll
        for (int r = 0; r < 4; ++r) {
          float x = acc[m][n][r] + b1v[n];
          float h = x / (1.f + __expf(-x));
          int row = wm * 64 + m * 16 + kgrp * 4 + r;
          int col = wn * 32 + n * 16 + lrow;
          *(short*)(Hb + row * 256 + ((col * 2) ^ ((row & 15) << 4))) = f2bf(h);
        }
    bar_lds();  // C: H visible (gathers(t+1) stay in flight)

    // ---- GEMM2: K=128 from H, B pinned ----
    f32x4 acc2[4][2];
#pragma unroll
    for (int m = 0; m < 4; ++m)
#pragma unroll
      for (int n = 0; n < 2; ++n) acc2[m][n] = (f32x4)0.f;
#pragma unroll
    for (int ks = 0; ks < 4; ++ks) {
      bf16x8 a[4];
#pragma unroll
      for (int m = 0; m < 4; ++m) {
        int row = wm * 64 + m * 16 + lrow;
        a[m] = *(const bf16x8*)(Hb + row * 256 +
                                ((ks * 64 + kgrp * 16) ^ ((row & 15) << 4)));
      }
#pragma unroll
      for (int m = 0; m < 4; ++m)
#pragma unroll
        for (int n = 0; n < 2; ++n)
          acc2[m][n] = __builtin_amdgcn_mfma_f32_16x16x32_bf16(a[m], B2r[ks][n],
                                                               acc2[m][n], 0, 0, 0);
    }

    // ---- x = acc2 + b2 -> xb (overlays cur[32K:64K); disjoint from H) ----
#pragma unroll
    for (int m = 0; m < 4; ++m)
#pragma unroll
      for (int n = 0; n < 2; ++n)
#pragma unroll
        for (int r = 0; r < 4; ++r) {
          float x = acc2[m][n][r] + b2v[n];
          int row = wm * 64 + m * 16 + kgrp * 4 + r;
          int col = wn * 32 + n * 16 + lrow;
          *(short*)(xb + row * 256 + ((col * 2) ^ ((row & 15) << 4))) = f2bf(x);
        }
    bar_lds();  // D: xb visible (all H reads complete)

    // ---- fused LN (4 thr/row, 2 shuffles) + residual(efb) + store ----
    {
      bf16x8 xv[4];
      float s1 = 0.f, s2 = 0.f;
#pragma unroll
      for (int c = 0; c < 4; ++c) {
        xv[c] = *(const bf16x8*)(xb + frow * 256 + ((fc * 2 + c * 16) ^ fswz));
#pragma unroll
        for (int j = 0; j < 8; ++j) {
          float f = bf2f(xv[c][j]);
          s1 += f;
          s2 += f * f;
        }
      }
      s1 += __shfl_xor(s1, 1, 64); s2 += __shfl_xor(s2, 1, 64);
      s1 += __shfl_xor(s1, 2, 64); s2 += __shfl_xor(s2, 2, 64);
      float mu = s1 * (1.f / 128.f);
      float var = s2 * (1.f / 128.f) - mu * mu;
      float rs = rsqrtf(var + LN_EPS);
      int e = t * 128 + frow;
      if (e < N_EDGES) {
        float* op = out + (size_t)e * 128 + fc;
#pragma unroll
        for (int c = 0; c < 4; ++c) {
          bf16x8 rv = *(const bf16x8*)(efb + frow * 256 +
                                       ((fc * 2 + c * 16) ^ fswz));
          f32x4 g0 = *(const f32x4*)(gamma + fc + c * 8);
          f32x4 g1 = *(const f32x4*)(gamma + fc + c * 8 + 4);
          f32x4 be0 = *(const f32x4*)(beta + fc + c * 8);
          f32x4 be1 = *(const f32x4*)(beta + fc + c * 8 + 4);
          f32x4 o0, o1;
#pragma unroll
          for (int j = 0; j < 4; ++j) {
            o0[j] = (bf2f(xv[c][j]) - mu) * rs * g0[j] + be0[j] + bf2f(rv[j]);
            o1[j] = (bf2f(xv[c][4 + j]) - mu) * rs * g1[j] + be1[j] +
                    bf2f(rv[4 + j]);
          }
          *(f32x4*)(op + c * 8) = o0;
          *(f32x4*)(op + c * 8 + 4) = o1;
        }
      }
    }
    // ef(t+1) -> efb, own rows (same thread just read its residual: no barrier)
    write_ef();
  }
  asm volatile("s_waitcnt vmcnt(0)" ::: "memory");
}

// ---- fallback (tiny ws): block-per-edge, fp32 ----
__global__ void edge_simple(const float* __restrict__ efeat, const float* __restrict__ nfeat,
                            const int* __restrict__ src, const int* __restrict__ dst,
                            const float* __restrict__ W1, const float* __restrict__ b1,
                            const float* __restrict__ W2, const float* __restrict__ b2,
                            const float* __restrict__ g, const float* __restrict__ be,
                            float* __restrict__ out) {
  int e = blockIdx.x, j = threadIdx.x;
  __shared__ float cat[384], h[128], red[128];
  cat[j] = efeat[(size_t)e * 128 + j];
  cat[128 + j] = nfeat[(size_t)src[e] * 128 + j];
  cat[256 + j] = nfeat[(size_t)dst[e] * 128 + j];
  __syncthreads();
  float s = b1[j];
  for (int k = 0; k < 384; ++k) s += cat[k] * W1[k * 128 + j];
  h[j] = s / (1.f + expf(-s));
  __syncthreads();
  float o = b2[j];
  for (int k = 0; k < 128; ++k) o += h[k] * W2[k * 128 + j];
  red[j] = o;
  __syncthreads();
  __shared__ float mu, rs;
  if (j == 0) {
    float s1 = 0, s2 = 0;
    for (int k = 0; k < 128; ++k) { s1 += red[k]; s2 += red[k] * red[k]; }
    mu = s1 / 128.f;
    rs = rsqrtf(s2 / 128.f - mu * mu + LN_EPS);
  }
  __syncthreads();
  out[(size_t)e * 128 + j] = (o - mu) * rs * g[j] + be[j] + efeat[(size_t)e * 128 + j];
}

extern "C" void kernel_launch(void* const* d_in, const int* in_sizes, int n_in,
                              void* d_out, int out_size, void* d_ws, size_t ws_size,
                              hipStream_t stream) {
  const float* efeat = (const float*)d_in[0];
  const float* nfeat = (const float*)d_in[1];
  const int* src = (const int*)d_in[2];
  const int* dst = (const int*)d_in[3];
  const float* W1 = (const float*)d_in[4];
  const float* b1 = (const float*)d_in[5];
  const float* W2 = (const float*)d_in[6];
  const float* b2 = (const float*)d_in[7];
  const float* gamma = (const float*)d_in[8];
  const float* beta = (const float*)d_in[9];
  float* out = (float*)d_out;

  short* w1t = (short*)d_ws;         // 96 KB
  short* w2t = w1t + 384 * 128;      // 32 KB
  short* nbf = w2t + 128 * 128;      // 12.8 MB
  const size_t need =
      (size_t)(384 * 128 + 128 * 128 + (size_t)N_NODES * 128) * sizeof(short);

  if (ws_size >= need) {
    convert_kernel<<<1024, 256, 0, stream>>>(W1, W2, nfeat, w1t, w2t, nbf,
                                             out + (size_t)N_EDGES * 128);
    edge_mlp_t128<<<GRID, 512, 0, stream>>>(efeat, nbf, src, dst, w1t, w2t,
                                            b1, b2, gamma, beta, out);
  } else {
    hipMemcpyAsync(out + (size_t)N_EDGES * 128, nfeat,
                   (size_t)N_NODES * 128 * sizeof(float),
                   hipMemcpyDeviceToDevice, stream);
    edge_simple<<<N_EDGES, 128, 0, stream>>>(efeat, nfeat, src, dst, W1, b1, W2,
                                             b2, gamma, beta, out);
  }
}

// Round 21
// 281.213 us; speedup vs baseline: 2.7596x; 1.4939x over previous
//
#include <hip/hip_runtime.h>
#include <hip/hip_bf16.h>

#define N_EDGES 500000
#define N_NODES 50000
#define NT ((N_EDGES + 63) / 64)  // 7813 tiles of 64 edges
#define GRID 256
#define LN_EPS 1e-5f

typedef __attribute__((ext_vector_type(8))) short bf16x8;
typedef __attribute__((ext_vector_type(4))) short bf16x4;
typedef __attribute__((ext_vector_type(4))) float f32x4;

static __device__ __forceinline__ short f2bf(float f) {
  return __builtin_bit_cast(short, __float2bfloat16(f));
}
static __device__ __forceinline__ float bf2f(short s) {
  unsigned u = ((unsigned)(unsigned short)s) << 16;
  return __builtin_bit_cast(float, u);
}
static __device__ __forceinline__ void gload16(const void* g, void* l) {
  __builtin_amdgcn_global_load_lds(
      (const __attribute__((address_space(1))) unsigned int*)g,
      (__attribute__((address_space(3))) unsigned int*)l, 16, 0, 0);
}
// pin a loaded value: asm results are not rematerializable -> stays in VGPRs
static __device__ __forceinline__ void pin(bf16x8& v) {
  asm volatile("" : "+v"(v));
}
// lgkm-only barrier: does NOT drain in-flight global_load_lds
static __device__ __forceinline__ void bar_lds() {
  __builtin_amdgcn_sched_barrier(0);
  asm volatile("s_waitcnt lgkmcnt(0)" ::: "memory");
  __builtin_amdgcn_s_barrier();
  __builtin_amdgcn_sched_barrier(0);
}
// counted barrier: FIFO = [gathers(t)4, stores(t-1)4, stageS4, gathers(t+1)4]
// -> vmcnt(8) drains gathers(t)+stores, keeps the fresh 8 in flight
static __device__ __forceinline__ void bar_vm8() {
  __builtin_amdgcn_sched_barrier(0);
  asm volatile("s_waitcnt vmcnt(8) lgkmcnt(0)" ::: "memory");
  __builtin_amdgcn_s_barrier();
  __builtin_amdgcn_sched_barrier(0);
}

// w1t [128n][384k] bf16, w2t [128n][128k] bf16, nbf = bf16(nfeat), + passthrough
__global__ void convert_kernel(const float* __restrict__ W1,
                               const float* __restrict__ W2,
                               const float* __restrict__ nfeat,
                               short* __restrict__ w1t, short* __restrict__ w2t,
                               short* __restrict__ nbf, float* __restrict__ outn) {
  const int step = gridDim.x * blockDim.x;
  const int t0 = blockIdx.x * blockDim.x + threadIdx.x;
  for (int i = t0; i < 384 * 128; i += step) {
    int n = i / 384, k = i - n * 384;
    w1t[i] = f2bf(W1[k * 128 + n]);
  }
  for (int i = t0; i < 128 * 128; i += step) {
    int n = i >> 7, k = i & 127;
    w2t[i] = f2bf(W2[k * 128 + n]);
  }
  for (int i = t0; i < N_NODES * 128 / 4; i += step) {
    f32x4 v = *(const f32x4*)(nfeat + (size_t)i * 4);
    short o4[4];
#pragma unroll
    for (int q = 0; q < 4; ++q) o4[q] = f2bf(v[q]);
    *(unsigned long long*)(nbf + (size_t)i * 4) = *(unsigned long long*)o4;
    *(f32x4*)(outn + (size_t)i * 4) = v;  // passthrough output 1
  }
}

// Persistent pipelined: 256 blocks (1/CU) x 512 thr (8 waves). Tile = 64 edges.
// Wave (wm,wn): rows [wm*32,+32) x cols [wn*32,+32). Weights PINNED in regs
// (opaque asm defeats remat/sinking). cat double-buffered; 3 barriers/tile.
__global__ __launch_bounds__(512, 2) void edge_mlp_pipelined(
    const float* __restrict__ efeat, const short* __restrict__ nbf,
    const int* __restrict__ src, const int* __restrict__ dst,
    const short* __restrict__ w1t, const short* __restrict__ w2t,
    const float* __restrict__ b1, const float* __restrict__ b2,
    const float* __restrict__ gamma, const float* __restrict__ beta,
    float* __restrict__ out) {
  // buf0 [0,49152): ef [64][256B] + gathers [64][512B] @ +16384 ; buf1 @49152
  // Hb @98304 [64][256B]; xb @114688 [64][256B]; gb @131072 [256]f32
  __shared__ __align__(16) char smem[132096];
  char* Hb = smem + 98304;
  char* xb = smem + 114688;
  float* gb = (float*)(smem + 131072);

  const int tid = threadIdx.x;
  const int lane = tid & 63;
  const int w = tid >> 6;
  const int wm = w >> 2;       // row-half 0/1
  const int wn = w & 3;        // col-quarter 0..3
  const int lrow = lane & 15;
  const int kgrp = (lane >> 4) & 3;
  if (tid < 256) gb[tid] = tid < 128 ? gamma[tid] : beta[tid - 128];

  // ---- weights loaded ONCE, pinned in registers (non-rematerializable) ----
  bf16x8 B1r[12][2], B2r[4][2];
  float b1v[2], b2v[2];
#pragma unroll
  for (int n = 0; n < 2; ++n) {
    const int c = wn * 32 + n * 16 + lrow;
    b1v[n] = b1[c];
    b2v[n] = b2[c];
#pragma unroll
    for (int ks = 0; ks < 12; ++ks) {
      B1r[ks][n] = *(const bf16x8*)(w1t + c * 384 + ks * 32 + kgrp * 8);
      pin(B1r[ks][n]);
    }
#pragma unroll
    for (int ks = 0; ks < 4; ++ks) {
      B2r[ks][n] = *(const bf16x8*)(w2t + c * 128 + ks * 32 + kgrp * 8);
      pin(B2r[ks][n]);
    }
  }

  // gather statics: 4 gload16/wave/tile; pre-swizzled source (involution)
  int grow[4], goff[4], gseg[4];
#pragma unroll
  for (int i = 0; i < 4; ++i) {
    int F = w * 4096 + i * 1024 + lane * 16;
    grow[i] = F >> 9;
    int win = F & 511;
    gseg[i] = win >> 8;
    goff[i] = (win & 255) ^ ((grow[i] & 15) << 4);
  }
  // stage/flush mapping: 8 threads/row, 16-B chunks
  const int frow = tid >> 3;
  const int fcb = tid & 7;
  const int fswz = (frow & 15) << 4;

  f32x4 S[4];
  auto stage_S = [&](int t) {
    int e = t * 64 + frow;
    e = e < N_EDGES ? e : (N_EDGES - 1);
#pragma unroll
    for (int it = 0; it < 4; ++it)
      S[it] = *(const f32x4*)(efeat + (size_t)e * 128 + (fcb + it * 8) * 4);
  };
  auto write_ef = [&](char* buf) {
#pragma unroll
    for (int it = 0; it < 4; ++it) {
      bf16x4 v;
#pragma unroll
      for (int j = 0; j < 4; ++j) v[j] = f2bf(S[it][j]);
      *(bf16x4*)(buf + frow * 256 + (((fcb + it * 8) * 8) ^ fswz)) = v;
    }
  };
  int idxN[4];
  auto load_idx = [&](int t, int* ix) {
#pragma unroll
    for (int i = 0; i < 4; ++i) {
      int e = t * 64 + grow[i];
      e = e < N_EDGES ? e : (N_EDGES - 1);
      ix[i] = gseg[i] ? dst[e] : src[e];
    }
  };
  auto issue_g = [&](char* buf, const int* ix) {
#pragma unroll
    for (int i = 0; i < 4; ++i)
      gload16((const char*)nbf + (size_t)ix[i] * 256 + goff[i],
              buf + 16384 + w * 4096 + i * 1024);
  };

  // ---- prologue ----
  const int t0 = blockIdx.x;
  char* cur = smem;
  char* nxt = smem + 49152;
  {
    int ix0[4];
    load_idx(t0, ix0);
    stage_S(t0);
    write_ef(cur);
    issue_g(cur, ix0);
    load_idx(t0 + GRID, idxN);
  }

  for (int t = t0; t < NT; t += GRID) {
    stage_S(t + GRID);   // ef(t+1) -> regs
    issue_g(nxt, idxN);  // gathers(t+1) -> nxt
    bar_vm8();           // A: cur ready; fresh 8 loads stay in flight
    load_idx(t + 2 * GRID, idxN);

    // ---- GEMM1: K=384, rows wm*32..+32 from cur (B pinned in regs) ----
    f32x4 acc[2][2];
#pragma unroll
    for (int m = 0; m < 2; ++m)
#pragma unroll
      for (int n = 0; n < 2; ++n) acc[m][n] = (f32x4)0.f;
#pragma unroll
    for (int ks = 0; ks < 12; ++ks) {
      bf16x8 a[2];
#pragma unroll
      for (int m = 0; m < 2; ++m) {
        int row = wm * 32 + m * 16 + lrow;
        int sw = (row & 15) << 4;
        a[m] = (ks < 4)
                   ? *(const bf16x8*)(cur + row * 256 + ((ks * 64 + kgrp * 16) ^ sw))
                   : *(const bf16x8*)(cur + 16384 + row * 512 +
                                      (((ks - 4) * 64 + kgrp * 16) ^ sw));
      }
#pragma unroll
      for (int m = 0; m < 2; ++m)
#pragma unroll
        for (int n = 0; n < 2; ++n)
          acc[m][n] = __builtin_amdgcn_mfma_f32_16x16x32_bf16(a[m], B1r[ks][n],
                                                              acc[m][n], 0, 0, 0);
    }

    // ---- bias1 + SiLU -> Hb ----
#pragma unroll
    for (int m = 0; m < 2; ++m)
#pragma unroll
      for (int n = 0; n < 2; ++n)
#pragma unroll
        for (int r = 0; r < 4; ++r) {
          float x = acc[m][n][r] + b1v[n];
          float h = x / (1.f + __expf(-x));
          int row = wm * 32 + m * 16 + kgrp * 4 + r;
          int col = wn * 32 + n * 16 + lrow;
          *(short*)(Hb + row * 256 + ((col * 2) ^ ((row & 15) << 4))) = f2bf(h);
        }
    bar_lds();  // C: H visible (gathers stay in flight)

    // ---- GEMM2: K=128 from Hb (B pinned in regs) ----
    f32x4 acc2[2][2];
#pragma unroll
    for (int m = 0; m < 2; ++m)
#pragma unroll
      for (int n = 0; n < 2; ++n) acc2[m][n] = (f32x4)0.f;
#pragma unroll
    for (int ks = 0; ks < 4; ++ks) {
      bf16x8 a[2];
#pragma unroll
      for (int m = 0; m < 2; ++m) {
        int row = wm * 32 + m * 16 + lrow;
        a[m] = *(const bf16x8*)(Hb + row * 256 +
                                ((ks * 64 + kgrp * 16) ^ ((row & 15) << 4)));
      }
#pragma unroll
      for (int m = 0; m < 2; ++m)
#pragma unroll
        for (int n = 0; n < 2; ++n)
          acc2[m][n] = __builtin_amdgcn_mfma_f32_16x16x32_bf16(a[m], B2r[ks][n],
                                                               acc2[m][n], 0, 0, 0);
    }

    // ---- x = acc2 + b2 -> xb ----
#pragma unroll
    for (int m = 0; m < 2; ++m)
#pragma unroll
      for (int n = 0; n < 2; ++n)
#pragma unroll
        for (int r = 0; r < 4; ++r) {
          float x = acc2[m][n][r] + b2v[n];
          int row = wm * 32 + m * 16 + kgrp * 4 + r;
          int col = wn * 32 + n * 16 + lrow;
          *(short*)(xb + row * 256 + ((col * 2) ^ ((row & 15) << 4))) = f2bf(x);
        }
    bar_lds();  // D: x visible (all H reads complete)

    // ---- fused LN (6 shuffles) + residual + coalesced store ----
    {
      bf16x4 xv[4];
      float s1 = 0.f, s2 = 0.f;
#pragma unroll
      for (int it = 0; it < 4; ++it) {
        int c4 = fcb + it * 8;
        xv[it] = *(const bf16x4*)(xb + frow * 256 + ((c4 * 8) ^ fswz));
#pragma unroll
        for (int j = 0; j < 4; ++j) {
          float f = bf2f(xv[it][j]);
          s1 += f;
          s2 += f * f;
        }
      }
      s1 += __shfl_xor(s1, 1, 64); s2 += __shfl_xor(s2, 1, 64);
      s1 += __shfl_xor(s1, 2, 64); s2 += __shfl_xor(s2, 2, 64);
      s1 += __shfl_xor(s1, 4, 64); s2 += __shfl_xor(s2, 4, 64);
      float mu = s1 * (1.f / 128.f);
      float var = s2 * (1.f / 128.f) - mu * mu;
      float rs = rsqrtf(var + LN_EPS);
      int e = t * 64 + frow;
      if (e < N_EDGES) {
        float* op = out + (size_t)e * 128;
#pragma unroll
        for (int it = 0; it < 4; ++it) {
          int c4 = fcb + it * 8;
          bf16x4 rv = *(const bf16x4*)(cur + frow * 256 + ((c4 * 8) ^ fswz));
          f32x4 g = *(const f32x4*)(gb + c4 * 4);
          f32x4 be = *(const f32x4*)(gb + 128 + c4 * 4);
          f32x4 o;
#pragma unroll
          for (int j = 0; j < 4; ++j)
            o[j] = (bf2f(xv[it][j]) - mu) * rs * g[j] + be[j] + bf2f(rv[j]);
          *(f32x4*)(op + c4 * 4) = o;
        }
      }
    }
    write_ef(nxt);  // ef(t+1); visible at A(t+1) via lgkm drain
    char* tmp = cur; cur = nxt; nxt = tmp;
  }
  asm volatile("s_waitcnt vmcnt(0)" ::: "memory");
}

// ---- fallback (tiny ws): block-per-edge, fp32 ----
__global__ void edge_simple(const float* __restrict__ efeat, const float* __restrict__ nfeat,
                            const int* __restrict__ src, const int* __restrict__ dst,
                            const float* __restrict__ W1, const float* __restrict__ b1,
                            const float* __restrict__ W2, const float* __restrict__ b2,
                            const float* __restrict__ g, const float* __restrict__ be,
                            float* __restrict__ out) {
  int e = blockIdx.x, j = threadIdx.x;
  __shared__ float cat[384], h[128], red[128];
  cat[j] = efeat[(size_t)e * 128 + j];
  cat[128 + j] = nfeat[(size_t)src[e] * 128 + j];
  cat[256 + j] = nfeat[(size_t)dst[e] * 128 + j];
  __syncthreads();
  float s = b1[j];
  for (int k = 0; k < 384; ++k) s += cat[k] * W1[k * 128 + j];
  h[j] = s / (1.f + expf(-s));
  __syncthreads();
  float o = b2[j];
  for (int k = 0; k < 128; ++k) o += h[k] * W2[k * 128 + j];
  red[j] = o;
  __syncthreads();
  __shared__ float mu, rs;
  if (j == 0) {
    float s1 = 0, s2 = 0;
    for (int k = 0; k < 128; ++k) { s1 += red[k]; s2 += red[k] * red[k]; }
    mu = s1 / 128.f;
    rs = rsqrtf(s2 / 128.f - mu * mu + LN_EPS);
  }
  __syncthreads();
  out[(size_t)e * 128 + j] = (o - mu) * rs * g[j] + be[j] + efeat[(size_t)e * 128 + j];
}

extern "C" void kernel_launch(void* const* d_in, const int* in_sizes, int n_in,
                              void* d_out, int out_size, void* d_ws, size_t ws_size,
                              hipStream_t stream) {
  const float* efeat = (const float*)d_in[0];
  const float* nfeat = (const float*)d_in[1];
  const int* src = (const int*)d_in[2];
  const int* dst = (const int*)d_in[3];
  const float* W1 = (const float*)d_in[4];
  const float* b1 = (const float*)d_in[5];
  const float* W2 = (const float*)d_in[6];
  const float* b2 = (const float*)d_in[7];
  const float* gamma = (const float*)d_in[8];
  const float* beta = (const float*)d_in[9];
  float* out = (float*)d_out;

  short* w1t = (short*)d_ws;         // 96 KB
  short* w2t = w1t + 384 * 128;      // 32 KB
  short* nbf = w2t + 128 * 128;      // 12.8 MB
  const size_t need =
      (size_t)(384 * 128 + 128 * 128 + (size_t)N_NODES * 128) * sizeof(short);

  if (ws_size >= need) {
    convert_kernel<<<1024, 256, 0, stream>>>(W1, W2, nfeat, w1t, w2t, nbf,
                                             out + (size_t)N_EDGES * 128);
    edge_mlp_pipelined<<<GRID, 512, 0, stream>>>(efeat, nbf, src, dst, w1t, w2t,
                                                 b1, b2, gamma, beta, out);
  } else {
    hipMemcpyAsync(out + (size_t)N_EDGES * 128, nfeat,
                   (size_t)N_NODES * 128 * sizeof(float),
                   hipMemcpyDeviceToDevice, stream);
    edge_simple<<<N_EDGES, 128, 0, stream>>>(efeat, nfeat, src, dst, W1, b1, W2,
                                             b2, gamma, beta, out);
  }
}